// Round 4
// baseline (12589.505 us; speedup 1.0000x reference)
//
#include <hip/hip_runtime.h>

#define B_N 262144
#define T_STEPS 100
#define BETA_START 1e-4f
#define BETA_END 0.02f

typedef __bf16 bf16x8 __attribute__((ext_vector_type(8)));
typedef float f32x4 __attribute__((ext_vector_type(4)));

__device__ __forceinline__ float siluf(float z) {
  float e = __expf(-z);
  return z * __builtin_amdgcn_rcpf(1.0f + e);
}

__device__ __forceinline__ unsigned bbits(float f) {
  __bf16 h = (__bf16)f;
  return (unsigned)__builtin_bit_cast(unsigned short, h);
}
__device__ __forceinline__ unsigned pack2(float lo, float hi) {
  return bbits(lo) | (bbits(hi) << 16);
}
__device__ __forceinline__ float unlo(unsigned u) { return __uint_as_float(u << 16); }
__device__ __forceinline__ float unhi(unsigned u) { return __uint_as_float(u & 0xffff0000u); }

// 256 thr = 4 waves; each wave owns 16 rows (one 16x16 MFMA tile). Grid 4096.
// KEY (rounds 2/3 evidence): the 32 loop-invariant W2^T fragments (128 regs)
// get LICM-hoisted into arch VGPRs -> 244 arch -> either occ-1 (256,1) or
// spill hell (256,2). Fix: pin them in AGPRs ("+a" empty asm, no instrs);
// MFMA B reads AGPR directly (AV operand class). Arch stays ~75-110,
// total ~235 <= 256 -> 2 waves/SIMD, no spills, no main-loop W2 LDS traffic.
__global__ __launch_bounds__(256, 2) void diff_kernel(
    const float* __restrict__ ctx, const float* __restrict__ x_init,
    const float* __restrict__ noise, const float* __restrict__ W1,
    const float* __restrict__ b1, const float* __restrict__ W2,
    const float* __restrict__ b2, const float* __restrict__ W3,
    const float* __restrict__ b3, const float* __restrict__ temb,
    float* __restrict__ out) {
  __shared__ alignas(16) unsigned short sW[128][136];  // W^T bf16 bits (prologue only)
  __shared__ float sx[64];                             // per-row x broadcast
  __shared__ alignas(8) unsigned swxt[128];            // pack2(w1x[c], w1t[c])
  __shared__ float sb2[128];
  __shared__ float sw3[128];

  const int tid = threadIdx.x;
  const int lane = tid & 63;
  const int wv = tid >> 6;   // wave 0..3
  const int ar = lane & 15;  // A-frag row / C-frag col-low
  const int kg = lane >> 4;  // 0..3 k-group
  const int rowW = blockIdx.x * 64 + wv * 16;

  // ---- stage W1[:128]^T as bf16; small tables ----
  for (int i = tid; i < 128 * 128; i += 256) {
    int k = i >> 7, n = i & 127;
    sW[n][k] = (unsigned short)bbits(W1[i]);
  }
  if (tid < 128) {
    swxt[tid] = pack2(W1[128 * 128 + tid], W1[129 * 128 + tid]);
    sb2[tid] = b2[tid];
    sw3[tid] = W3[tid];
  }
  __syncthreads();

  // ---- C1 = ctx @ W1[:128] + b1 ----
  f32x4 acc[8];
#pragma unroll
  for (int nt = 0; nt < 8; ++nt) {
    float b1c = b1[nt * 16 + ar];
    acc[nt] = (f32x4){b1c, b1c, b1c, b1c};
  }
  {
    const float4* crow4 = reinterpret_cast<const float4*>(ctx + (size_t)(rowW + ar) * 128);
    bf16x8 caf[4];
#pragma unroll
    for (int kk = 0; kk < 4; ++kk) {
      float4 a = crow4[kk * 8 + kg * 2];
      float4 b = crow4[kk * 8 + kg * 2 + 1];
      caf[kk][0] = (__bf16)a.x; caf[kk][1] = (__bf16)a.y;
      caf[kk][2] = (__bf16)a.z; caf[kk][3] = (__bf16)a.w;
      caf[kk][4] = (__bf16)b.x; caf[kk][5] = (__bf16)b.y;
      caf[kk][6] = (__bf16)b.z; caf[kk][7] = (__bf16)b.w;
    }
#pragma unroll
    for (int kk = 0; kk < 4; ++kk)
#pragma unroll
      for (int nt = 0; nt < 8; ++nt) {
        bf16x8 bf = *reinterpret_cast<const bf16x8*>(&sW[nt * 16 + ar][kk * 32 + kg * 8]);
        acc[nt] = __builtin_amdgcn_mfma_f32_16x16x32_bf16(caf[kk], bf, acc[nt], 0, 0, 0);
      }
  }
  __syncthreads();  // done reading W1^T

  // ---- transpose C-layout -> A-layout via LDS scratch (aliases sW) ----
  unsigned c1p[4][4];
  {
    float* scr = reinterpret_cast<float*>(&sW[0][0]) + wv * 2112;  // 16x132 f32 per wave
#pragma unroll
    for (int nt = 0; nt < 8; ++nt)
#pragma unroll
      for (int r = 0; r < 4; ++r)
        scr[(kg * 4 + r) * 132 + nt * 16 + ar] = acc[nt][r];
    asm volatile("s_waitcnt lgkmcnt(0)" ::: "memory");
#pragma unroll
    for (int kk = 0; kk < 4; ++kk)
#pragma unroll
      for (int jj = 0; jj < 4; ++jj) {
        float f0 = scr[ar * 132 + kk * 32 + kg * 8 + jj * 2];
        float f1 = scr[ar * 132 + kk * 32 + kg * 8 + jj * 2 + 1];
        c1p[kk][jj] = pack2(f0, f1);
      }
    asm volatile("s_waitcnt lgkmcnt(0)" ::: "memory");
  }
  __syncthreads();  // scratch reads done

  // ---- stage W2^T as bf16 ----
  for (int i = tid; i < 128 * 128; i += 256) {
    int k = i >> 7, n = i & 127;
    sW[n][k] = (unsigned short)bbits(W2[i]);
  }
  __syncthreads();

  // ---- W2 fragments -> registers once; pinned to AGPRs in the loop ----
  f32x4 w2a[32];
#pragma unroll
  for (int kk = 0; kk < 4; ++kk)
#pragma unroll
    for (int nt = 0; nt < 8; ++nt)
      w2a[kk * 8 + nt] =
          *reinterpret_cast<const f32x4*>(&sW[nt * 16 + ar][kk * 32 + kg * 8]);

  // ---- x init ----
  float xq[4];
#pragma unroll
  for (int r = 0; r < 4; ++r) xq[r] = x_init[rowW + kg * 4 + r];
  if (ar == 0) {
#pragma unroll
    for (int r = 0; r < 4; ++r) sx[wv * 16 + kg * 4 + r] = xq[r];
  }

  // ---- diffusion schedule ----
  const float db = (BETA_END - BETA_START) / 99.0f;
  float acp = 1.0f;
  for (int t = 0; t < T_STEPS; ++t) acp *= (1.0f - (BETA_START + (float)t * db));
  const float b3v = b3[0];

  for (int t = T_STEPS - 1; t >= 0; --t) {
    // Pin W2 fragments to AGPRs (no instructions; blocks arch-VGPR residency).
#pragma unroll
    for (int i = 0; i < 32; ++i) asm volatile("" : "+a"(w2a[i]));
    // Opaque zero: blocks LICM from hoisting swxt reads into arch VGPRs.
    int off = 0;
    asm volatile("" : "+v"(off));

    const float beta = BETA_START + (float)t * db;
    const float alpha = 1.0f - beta;
    const float c_pred = beta * __builtin_amdgcn_rsqf(1.0f - acp);
    const float c_x = __builtin_amdgcn_rsqf(alpha);
    const float c_n = (t > 0) ? __builtin_amdgcn_sqrtf(beta) : 0.0f;
    const float te = temb[t];

    const size_t noff = (size_t)(T_STEPS - 1 - t) * B_N + rowW + kg * 4;
    float er[4];
#pragma unroll
    for (int r = 0; r < 4; ++r) er[r] = noise[noff + r];
    const float xv = sx[wv * 16 + ar];

#pragma unroll
    for (int nt = 0; nt < 8; ++nt) {
      float b2v = sb2[nt * 16 + ar];
      acc[nt] = (f32x4){b2v, b2v, b2v, b2v};
    }

#pragma unroll
    for (int kk = 0; kk < 4; ++kk) {
      bf16x8 af;
#pragma unroll
      for (int jj = 0; jj < 4; ++jj) {
        const unsigned cp = c1p[kk][jj];
        const uint2 wp =
            *reinterpret_cast<const uint2*>(&swxt[off + kk * 32 + kg * 8 + 2 * jj]);
        float z0 = fmaf(te, unhi(wp.x), fmaf(xv, unlo(wp.x), unlo(cp)));
        float z1 = fmaf(te, unhi(wp.y), fmaf(xv, unlo(wp.y), unhi(cp)));
        af[2 * jj]     = (__bf16)siluf(z0);
        af[2 * jj + 1] = (__bf16)siluf(z1);
      }
#pragma unroll
      for (int nt = 0; nt < 8; ++nt) {
        acc[nt] = __builtin_amdgcn_mfma_f32_16x16x32_bf16(
            af, __builtin_bit_cast(bf16x8, w2a[kk * 8 + nt]), acc[nt], 0, 0, 0);
      }
    }

    // epilogue: h2 = silu(acc), pred = h2 . W3 + b3, x-update
    float p0 = 0.f, p1 = 0.f, p2 = 0.f, p3 = 0.f;
#pragma unroll
    for (int nt = 0; nt < 8; ++nt) {
      const float w3v = sw3[nt * 16 + ar];
      p0 = fmaf(siluf(acc[nt][0]), w3v, p0);
      p1 = fmaf(siluf(acc[nt][1]), w3v, p1);
      p2 = fmaf(siluf(acc[nt][2]), w3v, p2);
      p3 = fmaf(siluf(acc[nt][3]), w3v, p3);
    }
#pragma unroll
    for (int m = 1; m <= 8; m <<= 1) {
      p0 += __shfl_xor(p0, m, 64);
      p1 += __shfl_xor(p1, m, 64);
      p2 += __shfl_xor(p2, m, 64);
      p3 += __shfl_xor(p3, m, 64);
    }
    xq[0] = fmaf(c_n, er[0], (xq[0] - c_pred * (p0 + b3v)) * c_x);
    xq[1] = fmaf(c_n, er[1], (xq[1] - c_pred * (p1 + b3v)) * c_x);
    xq[2] = fmaf(c_n, er[2], (xq[2] - c_pred * (p2 + b3v)) * c_x);
    xq[3] = fmaf(c_n, er[3], (xq[3] - c_pred * (p3 + b3v)) * c_x);
    if (ar == 0) {
#pragma unroll
      for (int r = 0; r < 4; ++r) sx[wv * 16 + kg * 4 + r] = xq[r];
    }

    acp *= __builtin_amdgcn_rcpf(alpha);  // acp_{t-1} = acp_t / alpha_t
  }

  if (ar == 0) {
#pragma unroll
    for (int r = 0; r < 4; ++r) out[rowW + kg * 4 + r] = xq[r];
  }
}

extern "C" void kernel_launch(void* const* d_in, const int* in_sizes, int n_in,
                              void* d_out, int out_size, void* d_ws, size_t ws_size,
                              hipStream_t stream) {
  const float* ctx    = (const float*)d_in[0];
  const float* x_init = (const float*)d_in[1];
  const float* noise  = (const float*)d_in[2];
  const float* W1     = (const float*)d_in[3];
  const float* b1     = (const float*)d_in[4];
  const float* W2     = (const float*)d_in[5];
  const float* b2     = (const float*)d_in[6];
  const float* W3     = (const float*)d_in[7];
  const float* b3     = (const float*)d_in[8];
  const float* temb   = (const float*)d_in[9];
  float* out = (float*)d_out;

  diff_kernel<<<dim3(B_N / 64), dim3(256), 0, stream>>>(
      ctx, x_init, noise, W1, b1, W2, b2, W3, b3, temb, out);
}

// Round 6
// 3039.322 us; speedup vs baseline: 4.1422x; 4.1422x over previous
//
#include <hip/hip_runtime.h>

#define B_N 262144
#define T_STEPS 100
#define BETA_START 1e-4f
#define BETA_END 0.02f
#define NLOG2E (-1.44269504088896340736f)
#define NLN2 (-0.69314718055994530942f)

typedef _Float16 f16x8 __attribute__((ext_vector_type(8)));
typedef _Float16 f16x2 __attribute__((ext_vector_type(2)));
typedef float f32x4 __attribute__((ext_vector_type(4)));
typedef unsigned u32x4 __attribute__((ext_vector_type(4)));

__device__ __forceinline__ unsigned short f16b(float f) {
  return __builtin_bit_cast(unsigned short, (_Float16)f);
}

__device__ __forceinline__ unsigned pkrtz(float a, float b) {
  return __builtin_bit_cast(unsigned, __builtin_amdgcn_cvt_pkrtz(a, b));
}

// zs = -log2e * z  ->  returns -log2e * silu(z) = zs * sigmoid(z)
__device__ __forceinline__ float sscale(float zs) {
  float e = __builtin_amdgcn_exp2f(zs);  // = e^{-z}; TRANS hazard handled by compiler
  return zs * __builtin_amdgcn_rcpf(1.0f + e);
}

template <int CTRL>
__device__ __forceinline__ float rrot_add(float x) {
  int xi = __builtin_bit_cast(int, x);
  int yi = __builtin_amdgcn_update_dpp(xi, xi, CTRL, 0xf, 0xf, false);
  return x + __builtin_bit_cast(float, yi);
}
// Full sum over each 16-lane DPP row (our reduce axis ar = lane&15), VALU-only.
__device__ __forceinline__ float rowsum16(float x) {
  x = rrot_add<0x128>(x);  // row_ror:8
  x = rrot_add<0x124>(x);  // row_ror:4
  x = rrot_add<0x122>(x);  // row_ror:2
  x = rrot_add<0x121>(x);  // row_ror:1
  return x;
}

// 256 thr = 4 waves; each wave owns 32 rows (2x 16-row tiles). Grid 2048.
// W2 stays in LDS, re-read each step with LICM blocked via opaque `off`
// (round 3/4 lesson: hoisting = 128 VGPRs = spills; "+a" pinning = scratch hell).
// Exp2-prescale algebra: W1/b1/wxt staged *(-log2e), w3 *(-ln2), W2 unscaled;
// then v_exp_f32 needs no argument mul and acc IS the h2 exp2 argument.
__global__ __launch_bounds__(256, 2) void diff_kernel(
    const float* __restrict__ ctx, const float* __restrict__ x_init,
    const float* __restrict__ noise, const float* __restrict__ W1,
    const float* __restrict__ b1, const float* __restrict__ W2,
    const float* __restrict__ b2, const float* __restrict__ W3,
    const float* __restrict__ b3, const float* __restrict__ temb,
    float* __restrict__ out) {
  __shared__ alignas(16) unsigned short sW[128][136];  // f16 bits; W1' then W2
  __shared__ float sx[128];                            // per-row x broadcast

  const int tid = threadIdx.x;
  const int lane = tid & 63;
  const int wv = tid >> 6;   // wave 0..3
  const int ar = lane & 15;  // A-frag row / C-frag col-low
  const int kg = lane >> 4;  // 0..3 k-group
  const int rowW = blockIdx.x * 128 + wv * 32;

  // ---- stage W1[:128]^T * (-log2e) as f16 ----
  for (int i = tid; i < 128 * 128; i += 256) {
    int k = i >> 7, n = i & 127;
    sW[n][k] = f16b(NLOG2E * W1[i]);
  }
  __syncthreads();

  // ---- c1s = (-log2e)*(ctx @ W1[:128] + b1), f16 MFMA ----
  f32x4 acc[2][8];
#pragma unroll
  for (int nt = 0; nt < 8; ++nt) {
    float v = NLOG2E * b1[nt * 16 + ar];
    acc[0][nt] = (f32x4){v, v, v, v};
    acc[1][nt] = acc[0][nt];
  }
  {
    f16x8 caf[2][4];
#pragma unroll
    for (int t2 = 0; t2 < 2; ++t2) {
      const float4* crow4 =
          reinterpret_cast<const float4*>(ctx + (size_t)(rowW + t2 * 16 + ar) * 128);
#pragma unroll
      for (int kk = 0; kk < 4; ++kk) {
        float4 a = crow4[kk * 8 + kg * 2];
        float4 b = crow4[kk * 8 + kg * 2 + 1];
        caf[t2][kk][0] = (_Float16)a.x; caf[t2][kk][1] = (_Float16)a.y;
        caf[t2][kk][2] = (_Float16)a.z; caf[t2][kk][3] = (_Float16)a.w;
        caf[t2][kk][4] = (_Float16)b.x; caf[t2][kk][5] = (_Float16)b.y;
        caf[t2][kk][6] = (_Float16)b.z; caf[t2][kk][7] = (_Float16)b.w;
      }
    }
#pragma unroll
    for (int kk = 0; kk < 4; ++kk)
#pragma unroll
      for (int nt = 0; nt < 8; ++nt) {
        f16x8 bf = *reinterpret_cast<const f16x8*>(&sW[nt * 16 + ar][kk * 32 + kg * 8]);
        acc[0][nt] = __builtin_amdgcn_mfma_f32_16x16x32_f16(caf[0][kk], bf, acc[0][nt], 0, 0, 0);
        acc[1][nt] = __builtin_amdgcn_mfma_f32_16x16x32_f16(caf[1][kk], bf, acc[1][nt], 0, 0, 0);
      }
  }
  __syncthreads();  // done reading W1'

  // ---- transpose C-layout -> A-layout via LDS scratch; pack f16 pairs ----
  unsigned c1p[2][4][4];
  {
    float* scr = reinterpret_cast<float*>(&sW[0][0]) + wv * 2112;  // 16x132 f32/wave
#pragma unroll
    for (int t2 = 0; t2 < 2; ++t2) {
#pragma unroll
      for (int nt = 0; nt < 8; ++nt)
#pragma unroll
        for (int r = 0; r < 4; ++r)
          scr[(kg * 4 + r) * 132 + nt * 16 + ar] = acc[t2][nt][r];
      asm volatile("s_waitcnt lgkmcnt(0)" ::: "memory");
#pragma unroll
      for (int kk = 0; kk < 4; ++kk)
#pragma unroll
        for (int jj = 0; jj < 4; ++jj) {
          float f0 = scr[ar * 132 + kk * 32 + kg * 8 + jj * 2];
          float f1 = scr[ar * 132 + kk * 32 + kg * 8 + jj * 2 + 1];
          c1p[t2][kk][jj] = pkrtz(f0, f1);
        }
      asm volatile("s_waitcnt lgkmcnt(0)" ::: "memory");
    }
  }
  __syncthreads();  // scratch reads done

  // ---- stage W2^T as f16 (UNSCALED: (-ln2)*(-log2e) = 1 folds away) ----
  for (int i = tid; i < 128 * 128; i += 256) {
    int k = i >> 7, n = i & 127;
    sW[n][k] = f16b(W2[i]);
  }

  // ---- small per-lane constant tables in REGISTERS (loop-invariant) ----
  unsigned wx2[4][4], wt2[4][4];
#pragma unroll
  for (int kk = 0; kk < 4; ++kk)
#pragma unroll
    for (int jj = 0; jj < 4; ++jj) {
      int c = kk * 32 + kg * 8 + 2 * jj;
      wx2[kk][jj] = pkrtz(NLOG2E * W1[128 * 128 + c], NLOG2E * W1[128 * 128 + c + 1]);
      wt2[kk][jj] = pkrtz(NLOG2E * W1[129 * 128 + c], NLOG2E * W1[129 * 128 + c + 1]);
    }
  float w3r[8], b2s[8];
#pragma unroll
  for (int nt = 0; nt < 8; ++nt) {
    w3r[nt] = NLN2 * W3[nt * 16 + ar];
    b2s[nt] = NLOG2E * b2[nt * 16 + ar];
  }

  // ---- x init ----
  float xq[2][4];
#pragma unroll
  for (int t2 = 0; t2 < 2; ++t2)
#pragma unroll
    for (int r = 0; r < 4; ++r)
      xq[t2][r] = x_init[rowW + t2 * 16 + kg * 4 + r];
  if (ar == 0) {
#pragma unroll
    for (int t2 = 0; t2 < 2; ++t2)
#pragma unroll
      for (int r = 0; r < 4; ++r)
        sx[wv * 32 + t2 * 16 + kg * 4 + r] = xq[t2][r];
  }

  // ---- diffusion schedule ----
  const float db = (BETA_END - BETA_START) / 99.0f;
  float acp = 1.0f;
  for (int t = 0; t < T_STEPS; ++t) acp *= (1.0f - (BETA_START + (float)t * db));
  const float b3v = b3[0];
  __syncthreads();  // W2 staged; barrier-free main loop (sx is wave-private)

  for (int t = T_STEPS - 1; t >= 0; --t) {
    int off = 0;
    asm volatile("" : "+v"(off));  // opaque: keeps sW reads un-hoistable

    const float beta = BETA_START + (float)t * db;
    const float alpha = 1.0f - beta;
    const float c_pred = beta * __builtin_amdgcn_rsqf(1.0f - acp);
    const float c_x = __builtin_amdgcn_rsqf(alpha);
    const float c_n = (t > 0) ? __builtin_amdgcn_sqrtf(beta) : 0.0f;
    const float te = temb[t];

    const float xv0 = sx[wv * 32 + ar];
    const float xv1 = sx[wv * 32 + 16 + ar];

#pragma unroll
    for (int nt = 0; nt < 8; ++nt) {
      acc[0][nt] = (f32x4){b2s[nt], b2s[nt], b2s[nt], b2s[nt]};
      acc[1][nt] = acc[0][nt];
    }

#pragma unroll
    for (int kk = 0; kk < 4; ++kk) {
      f16x8 af0, af1;
      {
        u32x4 a0, a1;
#pragma unroll
        for (int jj = 0; jj < 4; ++jj) {
          f16x2 cp0 = __builtin_bit_cast(f16x2, c1p[0][kk][jj]);
          f16x2 cp1 = __builtin_bit_cast(f16x2, c1p[1][kk][jj]);
          f16x2 wx = __builtin_bit_cast(f16x2, wx2[kk][jj]);
          f16x2 wt = __builtin_bit_cast(f16x2, wt2[kk][jj]);
          // v_fma_mix: f16 operands consumed packed, f32 accumulate
          float z00 = fmaf(te, (float)wt[0], fmaf(xv0, (float)wx[0], (float)cp0[0]));
          float z01 = fmaf(te, (float)wt[1], fmaf(xv0, (float)wx[1], (float)cp0[1]));
          float z10 = fmaf(te, (float)wt[0], fmaf(xv1, (float)wx[0], (float)cp1[0]));
          float z11 = fmaf(te, (float)wt[1], fmaf(xv1, (float)wx[1], (float)cp1[1]));
          a0[jj] = pkrtz(sscale(z00), sscale(z01));
          a1[jj] = pkrtz(sscale(z10), sscale(z11));
        }
        af0 = __builtin_bit_cast(f16x8, a0);
        af1 = __builtin_bit_cast(f16x8, a1);
      }
#pragma unroll
      for (int nt = 0; nt < 8; ++nt) {
        f16x8 bf =
            *reinterpret_cast<const f16x8*>(&sW[nt * 16 + ar][off + kk * 32 + kg * 8]);
        acc[0][nt] = __builtin_amdgcn_mfma_f32_16x16x32_f16(af0, bf, acc[0][nt], 0, 0, 0);
        acc[1][nt] = __builtin_amdgcn_mfma_f32_16x16x32_f16(af1, bf, acc[1][nt], 0, 0, 0);
      }
    }

    // epilogue: acc already = -log2e * h2pre; pred = sum sscale(acc)*w3r
    const size_t nbase = (size_t)(T_STEPS - 1 - t) * B_N + rowW;
#pragma unroll
    for (int t2 = 0; t2 < 2; ++t2) {
      float p0 = 0.f, p1 = 0.f, p2 = 0.f, p3 = 0.f;
#pragma unroll
      for (int nt = 0; nt < 8; ++nt) {
        p0 = fmaf(sscale(acc[t2][nt][0]), w3r[nt], p0);
        p1 = fmaf(sscale(acc[t2][nt][1]), w3r[nt], p1);
        p2 = fmaf(sscale(acc[t2][nt][2]), w3r[nt], p2);
        p3 = fmaf(sscale(acc[t2][nt][3]), w3r[nt], p3);
      }
      p0 = rowsum16(p0);
      p1 = rowsum16(p1);
      p2 = rowsum16(p2);
      p3 = rowsum16(p3);
      if (ar == 0) {
        const float* np = noise + nbase + t2 * 16 + kg * 4;
        xq[t2][0] = fmaf(c_n, np[0], (xq[t2][0] - c_pred * (p0 + b3v)) * c_x);
        xq[t2][1] = fmaf(c_n, np[1], (xq[t2][1] - c_pred * (p1 + b3v)) * c_x);
        xq[t2][2] = fmaf(c_n, np[2], (xq[t2][2] - c_pred * (p2 + b3v)) * c_x);
        xq[t2][3] = fmaf(c_n, np[3], (xq[t2][3] - c_pred * (p3 + b3v)) * c_x);
#pragma unroll
        for (int r = 0; r < 4; ++r)
          sx[wv * 32 + t2 * 16 + kg * 4 + r] = xq[t2][r];
      }
    }

    acp *= __builtin_amdgcn_rcpf(alpha);  // acp_{t-1} = acp_t / alpha_t
  }

  if (ar == 0) {
#pragma unroll
    for (int t2 = 0; t2 < 2; ++t2)
#pragma unroll
      for (int r = 0; r < 4; ++r)
        out[rowW + t2 * 16 + kg * 4 + r] = xq[t2][r];
  }
}

extern "C" void kernel_launch(void* const* d_in, const int* in_sizes, int n_in,
                              void* d_out, int out_size, void* d_ws, size_t ws_size,
                              hipStream_t stream) {
  const float* ctx    = (const float*)d_in[0];
  const float* x_init = (const float*)d_in[1];
  const float* noise  = (const float*)d_in[2];
  const float* W1     = (const float*)d_in[3];
  const float* b1     = (const float*)d_in[4];
  const float* W2     = (const float*)d_in[5];
  const float* b2     = (const float*)d_in[6];
  const float* W3     = (const float*)d_in[7];
  const float* b3     = (const float*)d_in[8];
  const float* temb   = (const float*)d_in[9];
  float* out = (float*)d_out;

  diff_kernel<<<dim3(B_N / 128), dim3(256), 0, stream>>>(
      ctx, x_init, noise, W1, b1, W2, b2, W3, b3, temb, out);
}